// Round 1
// baseline (779.355 us; speedup 1.0000x reference)
//
#include <hip/hip_runtime.h>
#include <hip/hip_bf16.h>

// MHCtxAttention: N=32, T=1500, ENC=1024, DEC=1024, A=512, H=4, HA=2048
// Outputs: ali (N*H*T = 192000 f32), ctx (N*1024 = 32768 f32), concat in d_out.

#define N_B   32
#define T_S   1500
#define ENC_D 1024
#define HA_D  2048
#define A_D   512
#define H_N   4

typedef short s8v  __attribute__((ext_vector_type(8)));
typedef float f32x4 __attribute__((ext_vector_type(4)));

__device__ __forceinline__ unsigned short f2bf(float f) {
    unsigned u = __float_as_uint(f);
    unsigned r = (u + 0x7FFFu + ((u >> 16) & 1u)) >> 16;
    return (unsigned short)r;
}
__device__ __forceinline__ float bf2f(unsigned short b) {
    return __uint_as_float(((unsigned)b) << 16);
}
__device__ __forceinline__ float fast_tanh(float x) {
    float e2 = __expf(2.0f * x);
    return 1.0f - __fdividef(2.0f, e2 + 1.0f);
}
__device__ __forceinline__ void gload_lds16(const void* g, void* l) {
    __builtin_amdgcn_global_load_lds(
        (const unsigned int __attribute__((address_space(1)))*)g,
        (unsigned int __attribute__((address_space(3)))*)l, 16, 0, 0);
}

// ---------------- 1. cast enc_pad f32 -> bf16 ----------------
__global__ void cast_x_k(const float4* __restrict__ in, ushort4* __restrict__ out, int n4) {
    for (int i = blockIdx.x * blockDim.x + threadIdx.x; i < n4; i += gridDim.x * blockDim.x) {
        float4 v = in[i];
        ushort4 o;
        o.x = f2bf(v.x); o.y = f2bf(v.y); o.z = f2bf(v.z); o.w = f2bf(v.w);
        out[i] = o;
    }
}

// ---------------- 2. transpose-cast W_key (1024 x 2048) -> Wt bf16 (2048 x 1024) ----------------
__global__ void transpose_wkey_k(const float* __restrict__ Wk, unsigned short* __restrict__ Wt) {
    __shared__ float ld[64][65];
    const int tid = threadIdx.x;
    const int tx = tid & 63, ty = tid >> 6;               // ty 0..3
    const int c0 = blockIdx.x * 64, d0 = blockIdx.y * 64; // c over HA, d over ENC
#pragma unroll
    for (int j = 0; j < 16; ++j)
        ld[ty + 4 * j][tx] = Wk[(size_t)(d0 + ty + 4 * j) * HA_D + c0 + tx];
    __syncthreads();
#pragma unroll
    for (int j = 0; j < 16; ++j)
        Wt[(size_t)(c0 + ty + 4 * j) * ENC_D + d0 + tx] = f2bf(ld[tx][ty + 4 * j]);
}

// ---------------- 3. dec_part = dec_prev @ W_dec  (32 x 2048, f32) ----------------
__global__ void decpart_k(const float* __restrict__ dec_prev, const float* __restrict__ W_dec,
                          float* __restrict__ dp) {
    int gid = blockIdx.x * 256 + threadIdx.x;     // 65536
    int col = gid & (HA_D - 1), n = gid >> 11;
    const float* xr = dec_prev + (size_t)n * 1024;
    float acc = 0.f;
#pragma unroll 8
    for (int d = 0; d < 1024; ++d) acc = fmaf(xr[d], W_dec[(size_t)d * HA_D + col], acc);
    dp[gid] = acc;
}

// ---------------- 4. fused score GEMM:  e[n,h,t] = sum_a w_conv[h,a]*tanh((X@Wk)[.,ha] + dec[n,ha]) ----
// grid 1500 = 375 mtiles x 4 heads, 512 threads (8 waves, wave grid 2x4 over 128x256 chunk)
__global__ __launch_bounds__(512, 2) void fused_score_k(
    const unsigned short* __restrict__ Xb, const unsigned short* __restrict__ Wt,
    const float* __restrict__ dec, const float* __restrict__ wconv,
    float* __restrict__ e_out) {
    __shared__ unsigned short As[128 * 64];   // [row][k] 16KB
    __shared__ unsigned short Bs[256 * 64];   // [col][k] 32KB
    __shared__ float e_s[128];

    const int tid = threadIdx.x;
    const int lane = tid & 63, wid = tid >> 6;
    const int wr = wid >> 2, wc = wid & 3;
    const int l15 = lane & 15, lhi = lane >> 4;

    // bijective XCD swizzle: consecutive wgids (4 heads of one mtile) land on one XCD
    const int NW = 1500, q = NW / 8, r = NW % 8; // 187, 4
    int orig = blockIdx.x;
    int xcd = orig & 7, lid = orig >> 3;
    int wgid = (xcd < r ? xcd * (q + 1) : r * (q + 1) + (xcd - r) * q) + lid;
    const int mtile = wgid >> 2, h = wgid & 3;
    const int r0 = mtile * 128;

    if (tid < 128) e_s[tid] = 0.f;

    f32x4 acc[4][4];
    for (int chunk = 0; chunk < 2; ++chunk) {
        const int cb = chunk * 256;
#pragma unroll
        for (int m = 0; m < 4; ++m)
#pragma unroll
            for (int n2 = 0; n2 < 4; ++n2) {
                f32x4 z = {0.f, 0.f, 0.f, 0.f};
                acc[m][n2] = z;
            }

        for (int ks = 0; ks < 16; ++ks) {
            const int kb = ks * 64;
#pragma unroll
            for (int rnd = 0; rnd < 2; ++rnd) {   // A: 128 rows x 64 k
                int li = rnd * 512 + tid;
                const unsigned short* src = Xb + (size_t)(r0 + (li >> 3)) * ENC_D + kb + (li & 7) * 8;
                gload_lds16(src, &As[li * 8]);
            }
#pragma unroll
            for (int rnd = 0; rnd < 4; ++rnd) {   // B: 256 cols x 64 k
                int li = rnd * 512 + tid;
                const unsigned short* src = Wt + (size_t)(h * A_D + cb + (li >> 3)) * ENC_D + kb + (li & 7) * 8;
                gload_lds16(src, &Bs[li * 8]);
            }
            __syncthreads();
#pragma unroll
            for (int kk = 0; kk < 2; ++kk) {
                s8v af[4], bfr[4];
#pragma unroll
                for (int m = 0; m < 4; ++m)
                    af[m] = *(const s8v*)&As[(wr * 64 + m * 16 + l15) * 64 + kk * 32 + lhi * 8];
#pragma unroll
                for (int n2 = 0; n2 < 4; ++n2)
                    bfr[n2] = *(const s8v*)&Bs[(wc * 64 + n2 * 16 + l15) * 64 + kk * 32 + lhi * 8];
#pragma unroll
                for (int m = 0; m < 4; ++m)
#pragma unroll
                    for (int n2 = 0; n2 < 4; ++n2)
                        acc[m][n2] = __builtin_amdgcn_mfma_f32_16x16x32_bf16(af[m], bfr[n2], acc[m][n2], 0, 0, 0);
            }
            __syncthreads();
        }

        // epilogue: v = acc + dec; s = sum_cols wconv*tanh(v); butterfly over lanes 0..15; LDS atomic
        float wv[4];
#pragma unroll
        for (int n2 = 0; n2 < 4; ++n2)
            wv[n2] = wconv[h * A_D + cb + wc * 64 + n2 * 16 + l15];
#pragma unroll
        for (int m = 0; m < 4; ++m) {
#pragma unroll
            for (int rg = 0; rg < 4; ++rg) {
                int row_l = wr * 64 + m * 16 + lhi * 4 + rg;
                int grow = r0 + row_l;
                int nn = (int)((unsigned)grow / 1500u);
                const float* dslice = dec + (size_t)nn * HA_D + h * A_D + cb;
                float s = 0.f;
#pragma unroll
                for (int n2 = 0; n2 < 4; ++n2) {
                    float v = acc[m][n2][rg] + dslice[wc * 64 + n2 * 16 + l15];
                    s += wv[n2] * fast_tanh(v);
                }
                s += __shfl_xor(s, 1); s += __shfl_xor(s, 2);
                s += __shfl_xor(s, 4); s += __shfl_xor(s, 8);
                if (l15 == 0) atomicAdd(&e_s[row_l], s);
            }
        }
    }
    __syncthreads();
    if (tid < 128) {
        int grow = r0 + tid;
        int nn = grow / 1500, tt = grow - nn * 1500;
        e_out[(size_t)(nn * H_N + h) * T_S + tt] = e_s[tid];
    }
}

// ---------------- 5. masked softmax over T -> ali (into d_out) ----------------
__global__ void softmax_k(const float* __restrict__ e, const int* __restrict__ enc_len,
                          float* __restrict__ ali) {
    const int tid = threadIdx.x, lane = tid & 63, wid = tid >> 6;
    const int n = blockIdx.x >> 2;
    const int len = enc_len[n];
    const float* row = e + (size_t)blockIdx.x * T_S;
    float* orow = ali + (size_t)blockIdx.x * T_S;
    __shared__ float red[4];
    float p[6];
    float mx = -__builtin_inff();
#pragma unroll
    for (int i = 0; i < 6; ++i) {
        int t = tid + i * 256;
        float v = -__builtin_inff();
        if (t < T_S && t < len) v = row[t];
        p[i] = v;
        mx = fmaxf(mx, v);
    }
#pragma unroll
    for (int o = 32; o; o >>= 1) mx = fmaxf(mx, __shfl_xor(mx, o));
    if (lane == 0) red[wid] = mx;
    __syncthreads();
    mx = fmaxf(fmaxf(red[0], red[1]), fmaxf(red[2], red[3]));
    __syncthreads();
    float sum = 0.f;
#pragma unroll
    for (int i = 0; i < 6; ++i) {
        float qv = (p[i] == -__builtin_inff()) ? 0.f : __expf(p[i] - mx);
        p[i] = qv;
        sum += qv;
    }
#pragma unroll
    for (int o = 32; o; o >>= 1) sum += __shfl_xor(sum, o);
    if (lane == 0) red[wid] = sum;
    __syncthreads();
    sum = red[0] + red[1] + red[2] + red[3];
    float inv = 1.0f / sum;
#pragma unroll
    for (int i = 0; i < 6; ++i) {
        int t = tid + i * 256;
        if (t < T_S) orow[t] = p[i] * inv;
    }
}

// ---------------- 6. wenc[n,h,d] = sum_t ali[n,h,t] * enc_pad[n,t,d]  (atomics over t-quarters) ----
__global__ void wenc_k(const unsigned short* __restrict__ Xb, const float* __restrict__ ali,
                       float* __restrict__ wenc) {
    const int tid = threadIdx.x;                        // 128
    const int n = blockIdx.x & 31, dc = (blockIdx.x >> 5) & 7, tq = blockIdx.x >> 8;
    const int d = dc * 128 + tid;
    const int t0 = tq * 375;
    __shared__ float alis[4][375];
    for (int i = tid; i < 1500; i += 128) {
        int hh = i / 375, tt = i - hh * 375;
        alis[hh][tt] = ali[(size_t)(n * H_N + hh) * T_S + t0 + tt];
    }
    __syncthreads();
    float a0 = 0.f, a1 = 0.f, a2 = 0.f, a3 = 0.f;
    const unsigned short* xp = Xb + (size_t)(n * T_S + t0) * ENC_D + d;
#pragma unroll 4
    for (int t = 0; t < 375; ++t) {
        float x = bf2f(xp[(size_t)t * ENC_D]);
        a0 = fmaf(alis[0][t], x, a0);
        a1 = fmaf(alis[1][t], x, a1);
        a2 = fmaf(alis[2][t], x, a2);
        a3 = fmaf(alis[3][t], x, a3);
    }
    atomicAdd(&wenc[(size_t)(n * H_N + 0) * ENC_D + d], a0);
    atomicAdd(&wenc[(size_t)(n * H_N + 1) * ENC_D + d], a1);
    atomicAdd(&wenc[(size_t)(n * H_N + 2) * ENC_D + d], a2);
    atomicAdd(&wenc[(size_t)(n * H_N + 3) * ENC_D + d], a3);
}

// ---------------- 7. ctxpre[n, ha] = wenc[n,h,:] @ W_enc[:, ha] + b_enc[ha] ----------------
__global__ void ctxpre_k(const float* __restrict__ wenc, const float* __restrict__ W_enc,
                         const float* __restrict__ b_enc, float* __restrict__ cpre) {
    int gid = blockIdx.x * 256 + threadIdx.x;  // 65536
    int col = gid & (HA_D - 1), n = gid >> 11, h = col >> 9;
    const float* wrow = wenc + (size_t)(n * H_N + h) * ENC_D;
    float acc = b_enc[col];
#pragma unroll 8
    for (int d = 0; d < 1024; ++d) acc = fmaf(wrow[d], W_enc[(size_t)d * HA_D + col], acc);
    cpre[gid] = acc;
}

// ---------------- 8. ctx[n, j] = ctxpre[n,:] @ W_ctx[:, j] + b_ctx[j] ----------------
__global__ void ctx_k(const float* __restrict__ cpre, const float* __restrict__ W_ctx,
                      const float* __restrict__ b_ctx, float* __restrict__ out) {
    int gid = blockIdx.x * 256 + threadIdx.x;  // 32768
    int j = gid & (ENC_D - 1), n = gid >> 10;
    const float* cr = cpre + (size_t)n * HA_D;
    float acc = b_ctx[j];
#pragma unroll 8
    for (int p = 0; p < 2048; ++p) acc = fmaf(cr[p], W_ctx[(size_t)p * ENC_D + j], acc);
    out[gid] = acc;
}

extern "C" void kernel_launch(void* const* d_in, const int* in_sizes, int n_in,
                              void* d_out, int out_size, void* d_ws, size_t ws_size,
                              hipStream_t stream) {
    const float* enc_pad  = (const float*)d_in[0];
    const int*   enc_len  = (const int*)d_in[1];
    const float* dec_prev = (const float*)d_in[2];
    // d_in[3] = ali_prev (unused by forward)
    const float* W_enc    = (const float*)d_in[4];
    const float* b_enc    = (const float*)d_in[5];
    const float* W_key    = (const float*)d_in[6];
    const float* W_dec    = (const float*)d_in[7];
    const float* W_ctx    = (const float*)d_in[8];
    const float* b_ctx    = (const float*)d_in[9];
    const float* w_conv   = (const float*)d_in[10];

    char* ws = (char*)d_ws;
    unsigned short* Xb = (unsigned short*)ws;                 // 48000*1024*2 = 98,304,000
    unsigned short* Wt = (unsigned short*)(ws + 98304000);    // 2048*1024*2 =  4,194,304
    float* dp   = (float*)(ws + 102498304);                   // 32*2048*4   =    262,144
    float* e    = (float*)(ws + 102760448);                   // 192000*4    =    768,000
    float* wenc = (float*)(ws + 103528448);                   // 131072*4    =    524,288
    float* cpre = (float*)(ws + 104052736);                   // 65536*4     =    262,144

    float* ali = (float*)d_out;            // 192000
    float* ctx = ((float*)d_out) + 192000; // 32768

    cast_x_k<<<3000, 256, 0, stream>>>((const float4*)enc_pad, (ushort4*)Xb, 12288000);
    transpose_wkey_k<<<dim3(32, 16), 256, 0, stream>>>(W_key, Wt);
    decpart_k<<<256, 256, 0, stream>>>(dec_prev, W_dec, dp);
    fused_score_k<<<1500, 512, 0, stream>>>(Xb, Wt, dp, w_conv, e);
    softmax_k<<<128, 256, 0, stream>>>(e, enc_len, ali);
    hipMemsetAsync(wenc, 0, 131072 * sizeof(float), stream);
    wenc_k<<<1024, 128, 0, stream>>>(Xb, ali, wenc);
    ctxpre_k<<<256, 256, 0, stream>>>(wenc, W_enc, b_enc, cpre);
    ctx_k<<<128, 256, 0, stream>>>(cpre, W_ctx, b_ctx, ctx);
}

// Round 2
// 722.555 us; speedup vs baseline: 1.0786x; 1.0786x over previous
//
#include <hip/hip_runtime.h>
#include <hip/hip_bf16.h>

// MHCtxAttention: N=32, T=1500, ENC=1024, DEC=1024, A=512, H=4, HA=2048
// Outputs: ali (N*H*T = 192000 f32), ctx (N*1024 = 32768 f32), concat in d_out.

#define N_B   32
#define T_S   1500
#define ENC_D 1024
#define HA_D  2048
#define A_D   512
#define H_N   4
#define MROWS 48000   // N_B * T_S

typedef short s8v  __attribute__((ext_vector_type(8)));
typedef float f32x4 __attribute__((ext_vector_type(4)));

__device__ __forceinline__ unsigned short f2bf(float f) {
    unsigned u = __float_as_uint(f);
    unsigned r = (u + 0x7FFFu + ((u >> 16) & 1u)) >> 16;
    return (unsigned short)r;
}
__device__ __forceinline__ float bf2f(unsigned short b) {
    return __uint_as_float(((unsigned)b) << 16);
}
__device__ __forceinline__ float fast_tanh(float x) {
    float e2 = __expf(2.0f * x);
    return 1.0f - __fdividef(2.0f, e2 + 1.0f);
}
__device__ __forceinline__ void gload_lds16(const void* g, void* l) {
    __builtin_amdgcn_global_load_lds(
        (const unsigned int __attribute__((address_space(1)))*)g,
        (unsigned int __attribute__((address_space(3)))*)l, 16, 0, 0);
}

#define BARRIER() do { asm volatile("" ::: "memory"); __builtin_amdgcn_s_barrier(); asm volatile("" ::: "memory"); } while (0)

// ---------------- 1. cast enc_pad f32 -> bf16 ----------------
__global__ void cast_x_k(const float4* __restrict__ in, ushort4* __restrict__ out, int n4) {
    for (int i = blockIdx.x * blockDim.x + threadIdx.x; i < n4; i += gridDim.x * blockDim.x) {
        float4 v = in[i];
        ushort4 o;
        o.x = f2bf(v.x); o.y = f2bf(v.y); o.z = f2bf(v.z); o.w = f2bf(v.w);
        out[i] = o;
    }
}

// ---------------- 2. transpose-cast W_key (1024 x 2048) -> Wt bf16 (2048 x 1024) ----------------
__global__ void transpose_wkey_k(const float* __restrict__ Wk, unsigned short* __restrict__ Wt) {
    __shared__ float ld[64][65];
    const int tid = threadIdx.x;
    const int tx = tid & 63, ty = tid >> 6;               // ty 0..3
    const int c0 = blockIdx.x * 64, d0 = blockIdx.y * 64; // c over HA, d over ENC
#pragma unroll
    for (int j = 0; j < 16; ++j)
        ld[ty + 4 * j][tx] = Wk[(size_t)(d0 + ty + 4 * j) * HA_D + c0 + tx];
    __syncthreads();
#pragma unroll
    for (int j = 0; j < 16; ++j)
        Wt[(size_t)(c0 + ty + 4 * j) * ENC_D + d0 + tx] = f2bf(ld[tx][ty + 4 * j]);
}

// ---------------- 3. dec_part = dec_prev @ W_dec  (32 x 2048, f32) ----------------
__global__ void decpart_k(const float* __restrict__ dec_prev, const float* __restrict__ W_dec,
                          float* __restrict__ dp) {
    int gid = blockIdx.x * 256 + threadIdx.x;     // 65536
    int col = gid & (HA_D - 1), n = gid >> 11;
    const float* xr = dec_prev + (size_t)n * 1024;
    float acc = 0.f;
#pragma unroll 8
    for (int d = 0; d < 1024; ++d) acc = fmaf(xr[d], W_dec[(size_t)d * HA_D + col], acc);
    dp[gid] = acc;
}

// ---------------- 4. fused score GEMM, 256x256 tile, 8-wave, dbuf + counted vmcnt + swizzle ----
// grid 1504 = 188 mtiles x (4 heads x 2 col-chunks). e_out must be pre-zeroed (2 blocks add per elem).

__device__ __forceinline__ void stage_A_half(const unsigned short* __restrict__ Xb,
        unsigned short* Ab, int ha, int kb, int r0, int tid) {
#pragma unroll
    for (int ld = 0; ld < 2; ++ld) {
        int li = ld * 512 + tid;                 // [0,1024) -> 128 rows x 8 chunks
        int rowL = ha * 128 + (li >> 3);
        int c16 = li & 7;
        unsigned grow = (unsigned)(r0 + rowL);
        if (grow > (unsigned)(MROWS - 1)) grow = MROWS - 1;   // tail clamp (values discarded)
        const unsigned short* src = Xb + (size_t)grow * ENC_D + kb + ((c16 ^ (rowL & 7)) << 3);
        gload_lds16(src, Ab + ha * 8192 + li * 8);
    }
}
__device__ __forceinline__ void stage_B_half(const unsigned short* __restrict__ Wt,
        unsigned short* Bb, int hb, int kb, int bcol0, int tid) {
#pragma unroll
    for (int ld = 0; ld < 2; ++ld) {
        int li = ld * 512 + tid;
        int colL = hb * 128 + (li >> 3);
        int c16 = li & 7;
        const unsigned short* src = Wt + (size_t)(bcol0 + colL) * ENC_D + kb + ((c16 ^ (colL & 7)) << 3);
        gload_lds16(src, Bb + hb * 8192 + li * 8);
    }
}

#define PHASE(CC, MH, PF) do { \
    s8v af_[4]; \
    _Pragma("unroll") \
    for (int i_ = 0; i_ < 4; ++i_) \
        af_[i_] = *(const s8v*)&Ac[(arow + (MH) * 64 + i_ * 16) * 64 + (CC)]; \
    if ((MH) == 0) { \
        _Pragma("unroll") \
        for (int n_ = 0; n_ < 4; ++n_) \
            bf[n_] = *(const s8v*)&Bc[(bcol + n_ * 16) * 64 + (CC)]; \
    } \
    PF; \
    BARRIER(); \
    __builtin_amdgcn_s_setprio(1); \
    _Pragma("unroll") \
    for (int i_ = 0; i_ < 4; ++i_) { \
        _Pragma("unroll") \
        for (int n_ = 0; n_ < 4; ++n_) \
            acc[(MH) * 4 + i_][n_] = __builtin_amdgcn_mfma_f32_16x16x32_bf16(af_[i_], bf[n_], acc[(MH) * 4 + i_][n_], 0, 0, 0); \
    } \
    __builtin_amdgcn_s_setprio(0); \
    BARRIER(); \
} while (0)

__global__ __launch_bounds__(512, 2) void fused_score_k(
    const unsigned short* __restrict__ Xb, const unsigned short* __restrict__ Wt,
    const float* __restrict__ dec, const float* __restrict__ wconv,
    float* __restrict__ e_out) {
    __shared__ unsigned short As[2][16384];   // [buf][256 rows][64 k] 64KB
    __shared__ unsigned short Bs[2][16384];   // [buf][256 cols][64 k] 64KB
    __shared__ float e_s[256];

    const int tid = threadIdx.x;
    const int lane = tid & 63, wid = tid >> 6;
    const int wr = wid >> 2, wc = wid & 3;          // wave grid 2 (M) x 4 (N)
    const int l15 = lane & 15, lhi = lane >> 4;

    // bijective chunked XCD swizzle: nwg=1504, q=188, r=0; consecutive wgids share an XCD
    int orig = blockIdx.x;
    int wgid = (orig & 7) * 188 + (orig >> 3);
    const int mtile = wgid >> 3, ct = wgid & 7;
    const int h = ct >> 1, chunk = ct & 1;
    const int r0 = mtile * 256;
    const int bcol0 = h * A_D + chunk * 256;        // column base in Wt's HA dim

    if (tid < 256) e_s[tid] = 0.f;

    // swizzled fragment column offsets (ushort units): (kk*32 + lhi*8) ^ ((l15&7)<<3)
    const int cA0 = (lhi * 8) ^ ((l15 & 7) << 3);
    const int cA1 = (32 + lhi * 8) ^ ((l15 & 7) << 3);
    const int arow = wr * 128 + l15;
    const int bcol = wc * 64 + l15;

    f32x4 acc[8][4];
#pragma unroll
    for (int m = 0; m < 8; ++m)
#pragma unroll
        for (int n2 = 0; n2 < 4; ++n2) {
            f32x4 z = {0.f, 0.f, 0.f, 0.f};
            acc[m][n2] = z;
        }

    // prologue: tile0 fully + A-half0 of tile1; counted wait (2 in flight across barrier)
    stage_A_half(Xb, As[0], 0, 0, r0, tid);
    stage_A_half(Xb, As[0], 1, 0, r0, tid);
    stage_B_half(Wt, Bs[0], 0, 0, bcol0, tid);
    stage_B_half(Wt, Bs[0], 1, 0, bcol0, tid);
    stage_A_half(Xb, As[1], 0, 64, r0, tid);
    asm volatile("s_waitcnt vmcnt(2)" ::: "memory");
    __builtin_amdgcn_s_barrier();
    asm volatile("" ::: "memory");

    s8v bf[4];
    for (int kt = 0; kt < 16; ++kt) {
        const int cur = kt & 1, nxt = cur ^ 1;
        unsigned short* Ac = As[cur];
        unsigned short* Bc = Bs[cur];
        const int kbn = (kt + 1) << 6;
        // 4 phases: (kk, m-half). Prefetch ring issues halves of tile kt+1 oldest-first.
        PHASE(cA0, 0, { if (kt < 15) stage_A_half(Xb, As[nxt], 1, kbn, r0, tid); });
        PHASE(cA0, 1, { if (kt < 15) stage_B_half(Wt, Bs[nxt], 0, kbn, bcol0, tid); });
        PHASE(cA1, 0, { if (kt < 15) stage_B_half(Wt, Bs[nxt], 1, kbn, bcol0, tid); });
        PHASE(cA1, 1, {});
        // boundary: issue A-half0 of tile kt+2 into the buffer we just finished reading,
        // then counted wait: oldest 8 (= all of tile kt+1) done, 2 stay in flight.
        if (kt < 14) {
            stage_A_half(Xb, As[cur], 0, (kt + 2) << 6, r0, tid);
            asm volatile("s_waitcnt vmcnt(2)" ::: "memory");
        } else if (kt == 14) {
            asm volatile("s_waitcnt vmcnt(0)" ::: "memory");
        }
        BARRIER();
    }

    // fused epilogue: + dec, tanh, * w_conv, sum over a-cols (butterfly over l15), LDS atomic
    float wv[4];
#pragma unroll
    for (int n2 = 0; n2 < 4; ++n2)
        wv[n2] = wconv[bcol0 + wc * 64 + n2 * 16 + l15];
#pragma unroll
    for (int m = 0; m < 8; ++m) {
#pragma unroll
        for (int rg = 0; rg < 4; ++rg) {
            int row_l = wr * 128 + m * 16 + lhi * 4 + rg;
            int grow = r0 + row_l;
            if (grow < MROWS) {
                int nn = (int)((unsigned)grow / 1500u);
                const float* dsl = dec + (size_t)nn * HA_D + bcol0 + wc * 64 + l15;
                float s = 0.f;
#pragma unroll
                for (int n2 = 0; n2 < 4; ++n2) {
                    float v = acc[m][n2][rg] + dsl[n2 * 16];
                    s += wv[n2] * fast_tanh(v);
                }
                s += __shfl_xor(s, 1); s += __shfl_xor(s, 2);
                s += __shfl_xor(s, 4); s += __shfl_xor(s, 8);
                if (l15 == 0) atomicAdd(&e_s[row_l], s);
            }
        }
    }
    __syncthreads();
    if (tid < 256) {
        int grow = r0 + tid;
        if (grow < MROWS) {
            int nn = grow / 1500, tt = grow - nn * 1500;
            atomicAdd(&e_out[(size_t)(nn * H_N + h) * T_S + tt], e_s[tid]);
        }
    }
}

// ---------------- 5. masked softmax over T -> ali (into d_out) ----------------
__global__ void softmax_k(const float* __restrict__ e, const int* __restrict__ enc_len,
                          float* __restrict__ ali) {
    const int tid = threadIdx.x, lane = tid & 63, wid = tid >> 6;
    const int n = blockIdx.x >> 2;
    const int len = enc_len[n];
    const float* row = e + (size_t)blockIdx.x * T_S;
    float* orow = ali + (size_t)blockIdx.x * T_S;
    __shared__ float red[4];
    float p[6];
    float mx = -__builtin_inff();
#pragma unroll
    for (int i = 0; i < 6; ++i) {
        int t = tid + i * 256;
        float v = -__builtin_inff();
        if (t < T_S && t < len) v = row[t];
        p[i] = v;
        mx = fmaxf(mx, v);
    }
#pragma unroll
    for (int o = 32; o; o >>= 1) mx = fmaxf(mx, __shfl_xor(mx, o));
    if (lane == 0) red[wid] = mx;
    __syncthreads();
    mx = fmaxf(fmaxf(red[0], red[1]), fmaxf(red[2], red[3]));
    __syncthreads();
    float sum = 0.f;
#pragma unroll
    for (int i = 0; i < 6; ++i) {
        float qv = (p[i] == -__builtin_inff()) ? 0.f : __expf(p[i] - mx);
        p[i] = qv;
        sum += qv;
    }
#pragma unroll
    for (int o = 32; o; o >>= 1) sum += __shfl_xor(sum, o);
    if (lane == 0) red[wid] = sum;
    __syncthreads();
    sum = red[0] + red[1] + red[2] + red[3];
    float inv = 1.0f / sum;
#pragma unroll
    for (int i = 0; i < 6; ++i) {
        int t = tid + i * 256;
        if (t < T_S) orow[t] = p[i] * inv;
    }
}

// ---------------- 6. wenc[n,h,d] = sum_t ali[n,h,t] * enc_pad[n,t,d]  (vectorized bf16 loads) ----
__global__ void wenc_k(const unsigned short* __restrict__ Xb, const float* __restrict__ ali,
                       float* __restrict__ wenc) {
    const int tid = threadIdx.x;                        // 128
    const int n = blockIdx.x & 31, dc = (blockIdx.x >> 5) & 1, tq = blockIdx.x >> 6;
    const int d0 = dc * 512 + tid * 4;
    const int t0 = tq * 375;
    __shared__ float alis[4][376];
    for (int i = tid; i < 1500; i += 128) {
        int hh = i / 375, tt = i - hh * 375;
        alis[hh][tt] = ali[(size_t)(n * H_N + hh) * T_S + t0 + tt];
    }
    __syncthreads();
    float a[4][4] = {};
    const unsigned short* xp = Xb + (size_t)(n * T_S + t0) * ENC_D + d0;
#pragma unroll 2
    for (int t = 0; t < 375; ++t) {
        ushort4 xv = *(const ushort4*)&xp[(size_t)t * ENC_D];
        float x0 = bf2f(xv.x), x1 = bf2f(xv.y), x2 = bf2f(xv.z), x3 = bf2f(xv.w);
#pragma unroll
        for (int hh = 0; hh < 4; ++hh) {
            float al = alis[hh][t];
            a[hh][0] = fmaf(al, x0, a[hh][0]);
            a[hh][1] = fmaf(al, x1, a[hh][1]);
            a[hh][2] = fmaf(al, x2, a[hh][2]);
            a[hh][3] = fmaf(al, x3, a[hh][3]);
        }
    }
#pragma unroll
    for (int hh = 0; hh < 4; ++hh)
#pragma unroll
        for (int j = 0; j < 4; ++j)
            atomicAdd(&wenc[(size_t)(n * H_N + hh) * ENC_D + d0 + j], a[hh][j]);
}

// ---------------- 7. ctxpre[n, ha] = wenc[n,h,:] @ W_enc[:, ha] + b_enc[ha] ----------------
__global__ void ctxpre_k(const float* __restrict__ wenc, const float* __restrict__ W_enc,
                         const float* __restrict__ b_enc, float* __restrict__ cpre) {
    int gid = blockIdx.x * 256 + threadIdx.x;  // 65536
    int col = gid & (HA_D - 1), n = gid >> 11, hh = col >> 9;
    const float* wrow = wenc + (size_t)(n * H_N + hh) * ENC_D;
    float acc = b_enc[col];
#pragma unroll 8
    for (int d = 0; d < 1024; ++d) acc = fmaf(wrow[d], W_enc[(size_t)d * HA_D + col], acc);
    cpre[gid] = acc;
}

// ---------------- 8. ctx[n, j] = ctxpre[n,:] @ W_ctx[:, j] + b_ctx[j] ----------------
__global__ void ctx_k(const float* __restrict__ cpre, const float* __restrict__ W_ctx,
                      const float* __restrict__ b_ctx, float* __restrict__ out) {
    int gid = blockIdx.x * 256 + threadIdx.x;  // 32768
    int j = gid & (ENC_D - 1), n = gid >> 10;
    const float* cr = cpre + (size_t)n * HA_D;
    float acc = b_ctx[j];
#pragma unroll 8
    for (int p = 0; p < 2048; ++p) acc = fmaf(cr[p], W_ctx[(size_t)p * ENC_D + j], acc);
    out[gid] = acc;
}

extern "C" void kernel_launch(void* const* d_in, const int* in_sizes, int n_in,
                              void* d_out, int out_size, void* d_ws, size_t ws_size,
                              hipStream_t stream) {
    const float* enc_pad  = (const float*)d_in[0];
    const int*   enc_len  = (const int*)d_in[1];
    const float* dec_prev = (const float*)d_in[2];
    // d_in[3] = ali_prev (unused by forward)
    const float* W_enc    = (const float*)d_in[4];
    const float* b_enc    = (const float*)d_in[5];
    const float* W_key    = (const float*)d_in[6];
    const float* W_dec    = (const float*)d_in[7];
    const float* W_ctx    = (const float*)d_in[8];
    const float* b_ctx    = (const float*)d_in[9];
    const float* w_conv   = (const float*)d_in[10];

    char* ws = (char*)d_ws;
    unsigned short* Xb = (unsigned short*)ws;                 // 48000*1024*2 = 98,304,000
    unsigned short* Wt = (unsigned short*)(ws + 98304000);    // 2048*1024*2 =  4,194,304
    float* dp   = (float*)(ws + 102498304);                   // 32*2048*4   =    262,144
    float* e    = (float*)(ws + 102760448);                   // 192000*4    =    768,000
    float* wenc = (float*)(ws + 103528448);                   // 131072*4    =    524,288
    float* cpre = (float*)(ws + 104052736);                   // 65536*4     =    262,144

    float* ali = (float*)d_out;            // 192000
    float* ctx = ((float*)d_out) + 192000; // 32768

    cast_x_k<<<3000, 256, 0, stream>>>((const float4*)enc_pad, (ushort4*)Xb, 12288000);
    transpose_wkey_k<<<dim3(32, 16), 256, 0, stream>>>(W_key, Wt);
    decpart_k<<<256, 256, 0, stream>>>(dec_prev, W_dec, dp);
    hipMemsetAsync(e, 0, 192000 * sizeof(float), stream);
    fused_score_k<<<1504, 512, 0, stream>>>(Xb, Wt, dp, w_conv, e);
    softmax_k<<<128, 256, 0, stream>>>(e, enc_len, ali);
    hipMemsetAsync(wenc, 0, 131072 * sizeof(float), stream);
    wenc_k<<<256, 128, 0, stream>>>(Xb, ali, wenc);
    ctxpre_k<<<256, 256, 0, stream>>>(wenc, W_enc, b_enc, cpre);
    ctx_k<<<128, 256, 0, stream>>>(cpre, W_ctx, b_ctx, ctx);
}

// Round 3
// 569.918 us; speedup vs baseline: 1.3675x; 1.2678x over previous
//
#include <hip/hip_runtime.h>
#include <hip/hip_bf16.h>

// MHCtxAttention: N=32, T=1500, ENC=1024, DEC=1024, A=512, H=4, HA=2048
// Outputs: ali (N*H*T = 192000 f32), ctx (N*1024 = 32768 f32), concat in d_out.

#define N_B   32
#define T_S   1500
#define ENC_D 1024
#define HA_D  2048
#define A_D   512
#define H_N   4
#define MROWS 48000   // N_B * T_S

typedef short s8v  __attribute__((ext_vector_type(8)));
typedef float f32x4 __attribute__((ext_vector_type(4)));

__device__ __forceinline__ unsigned short f2bf(float f) {
    unsigned u = __float_as_uint(f);
    unsigned r = (u + 0x7FFFu + ((u >> 16) & 1u)) >> 16;
    return (unsigned short)r;
}
__device__ __forceinline__ float bf2f(unsigned short b) {
    return __uint_as_float(((unsigned)b) << 16);
}
__device__ __forceinline__ float fast_tanh(float x) {
    float e2 = __expf(2.0f * x);
    return 1.0f - __fdividef(2.0f, e2 + 1.0f);
}
__device__ __forceinline__ void gload_lds16(const void* g, void* l) {
    __builtin_amdgcn_global_load_lds(
        (const unsigned int __attribute__((address_space(1)))*)g,
        (unsigned int __attribute__((address_space(3)))*)l, 16, 0, 0);
}

#define BARRIER() do { asm volatile("" ::: "memory"); __builtin_amdgcn_s_barrier(); asm volatile("" ::: "memory"); } while (0)

// ============ skinny GEMM body: Y[n][c] (+)= sum_k X[n][k] * W[k][c]  (M=32) ============
// block: 256 cols (c0=ct*256) x 32 n x 64-k chunk (k0=ks*64). W read coalesced float4,
// X chunk staged transposed [kk][n] in LDS, consumed as wave-uniform broadcast b128.
// Accumulate via f32 atomicAdd; bias folded into ks==0 blocks. Y must be pre-zeroed.
__device__ __forceinline__ void skinny_body(
    int bid, const float* __restrict__ X, const float* __restrict__ W,
    const float* __restrict__ bias, float* __restrict__ Y,
    int Ncols, int ct_mask, int ct_shift, int xA, int xB, float* xT /* >= 64*36 floats */) {
    const int tid = threadIdx.x;
    const int ct = bid & ct_mask, ks = bid >> ct_shift;
    const int c0 = ct << 8, k0 = ks << 6;
    const int hsel = c0 >> 9;
    // stage xT[kk][n] = X[n*xA + hsel*xB + k0 + kk], stride 36 floats (16B-aligned rows)
    {
        const int n = tid >> 3, kk0 = (tid & 7) << 3;
        const float* xr = X + (size_t)n * xA + hsel * xB + k0 + kk0;
        float4 v0 = *(const float4*)xr;
        float4 v1 = *(const float4*)(xr + 4);
        xT[(kk0 + 0) * 36 + n] = v0.x;
        xT[(kk0 + 1) * 36 + n] = v0.y;
        xT[(kk0 + 2) * 36 + n] = v0.z;
        xT[(kk0 + 3) * 36 + n] = v0.w;
        xT[(kk0 + 4) * 36 + n] = v1.x;
        xT[(kk0 + 5) * 36 + n] = v1.y;
        xT[(kk0 + 6) * 36 + n] = v1.z;
        xT[(kk0 + 7) * 36 + n] = v1.w;
    }
    __syncthreads();
    const int w = tid >> 6, lane = tid & 63;
    f32x4 acc[8];
    if (bias != nullptr && ks == 0) {
        f32x4 bv = *(const f32x4*)&bias[c0 + (lane << 2)];
#pragma unroll
        for (int j = 0; j < 8; ++j) acc[j] = bv;
    } else {
#pragma unroll
        for (int j = 0; j < 8; ++j) { f32x4 z = {0.f, 0.f, 0.f, 0.f}; acc[j] = z; }
    }
    const float* Wp = W + (size_t)k0 * Ncols + c0 + (lane << 2);
#pragma unroll 4
    for (int kk = 0; kk < 64; ++kk) {
        f32x4 wf = *(const f32x4*)(Wp + (size_t)kk * Ncols);
        f32x4 xlo = *(const f32x4*)&xT[kk * 36 + w * 8];
        f32x4 xhi = *(const f32x4*)&xT[kk * 36 + w * 8 + 4];
#pragma unroll
        for (int j = 0; j < 4; ++j) {
            acc[j]     += xlo[j] * wf;
            acc[4 + j] += xhi[j] * wf;
        }
    }
#pragma unroll
    for (int j = 0; j < 8; ++j) {
        float* yp = Y + (size_t)(w * 8 + j) * Ncols + c0 + (lane << 2);
#pragma unroll
        for (int i = 0; i < 4; ++i) atomicAdd(yp + i, acc[j][i]);
    }
}

__global__ __launch_bounds__(256) void skinny_k(
    const float* __restrict__ X, const float* __restrict__ W,
    const float* __restrict__ bias, float* __restrict__ Y,
    int Ncols, int ct_mask, int ct_shift, int xA, int xB) {
    __shared__ float xT[64 * 36];
    skinny_body(blockIdx.x, X, W, bias, Y, Ncols, ct_mask, ct_shift, xA, xB, xT);
}

// ============ prep kernel: [0,128) dec_part skinny | [128,640) W_key transpose | [640,3640) cast ====
__global__ __launch_bounds__(256) void prep_k(
    const float* __restrict__ enc_pad, const float* __restrict__ Wk,
    const float* __restrict__ dec_prev, const float* __restrict__ W_dec,
    unsigned short* __restrict__ Xb, unsigned short* __restrict__ Wt,
    float* __restrict__ dp) {
    __shared__ float shmem[64 * 65];
    const int b = blockIdx.x;
    const int tid = threadIdx.x;
    if (b < 128) {
        // dec_part: dp[n][c] = dec_prev[n][:] @ W_dec[:][c];  N=2048, K=1024, 8ct x 16ks
        skinny_body(b, dec_prev, W_dec, nullptr, dp, HA_D, 7, 3, 1024, 0, shmem);
    } else if (b < 640) {
        // transpose-cast W_key (1024 x 2048) -> Wt bf16 (2048 x 1024)
        float (*ld)[65] = (float(*)[65])shmem;
        const int bb = b - 128;
        const int tx = tid & 63, ty = tid >> 6;
        const int c0 = (bb & 31) * 64, d0 = (bb >> 5) * 64;
#pragma unroll
        for (int j = 0; j < 16; ++j)
            ld[ty + 4 * j][tx] = Wk[(size_t)(d0 + ty + 4 * j) * HA_D + c0 + tx];
        __syncthreads();
#pragma unroll
        for (int j = 0; j < 16; ++j)
            Wt[(size_t)(c0 + ty + 4 * j) * ENC_D + d0 + tx] = f2bf(ld[tx][ty + 4 * j]);
    } else {
        // cast enc_pad f32 -> bf16 (12,288,000 float4 elements, 16 per thread)
        const float4* in = (const float4*)enc_pad;
        ushort4* out = (ushort4*)Xb;
        for (int i = (b - 640) * 256 + tid; i < 12288000; i += 3000 * 256) {
            float4 v = in[i];
            ushort4 o;
            o.x = f2bf(v.x); o.y = f2bf(v.y); o.z = f2bf(v.z); o.w = f2bf(v.w);
            out[i] = o;
        }
    }
}

// ============ fused score GEMM, 256x256 tile, 8-wave, dbuf + counted vmcnt + swizzle ============
// grid 1504 = 188 mtiles x (4 heads x 2 col-chunks). e_out must be pre-zeroed.

__device__ __forceinline__ void stage_A_half(const unsigned short* __restrict__ Xb,
        unsigned short* Ab, int ha, int kb, int r0, int tid) {
#pragma unroll
    for (int ld = 0; ld < 2; ++ld) {
        int li = ld * 512 + tid;
        int rowL = ha * 128 + (li >> 3);
        int c16 = li & 7;
        unsigned grow = (unsigned)(r0 + rowL);
        if (grow > (unsigned)(MROWS - 1)) grow = MROWS - 1;   // tail clamp (values discarded)
        const unsigned short* src = Xb + (size_t)grow * ENC_D + kb + ((c16 ^ (rowL & 7)) << 3);
        gload_lds16(src, Ab + ha * 8192 + li * 8);
    }
}
__device__ __forceinline__ void stage_B_half(const unsigned short* __restrict__ Wt,
        unsigned short* Bb, int hb, int kb, int bcol0, int tid) {
#pragma unroll
    for (int ld = 0; ld < 2; ++ld) {
        int li = ld * 512 + tid;
        int colL = hb * 128 + (li >> 3);
        int c16 = li & 7;
        const unsigned short* src = Wt + (size_t)(bcol0 + colL) * ENC_D + kb + ((c16 ^ (colL & 7)) << 3);
        gload_lds16(src, Bb + hb * 8192 + li * 8);
    }
}

#define PHASE(CC, MH, PF) do { \
    s8v af_[4]; \
    _Pragma("unroll") \
    for (int i_ = 0; i_ < 4; ++i_) \
        af_[i_] = *(const s8v*)&Ac[(arow + (MH) * 64 + i_ * 16) * 64 + (CC)]; \
    if ((MH) == 0) { \
        _Pragma("unroll") \
        for (int n_ = 0; n_ < 4; ++n_) \
            bf[n_] = *(const s8v*)&Bc[(bcol + n_ * 16) * 64 + (CC)]; \
    } \
    PF; \
    BARRIER(); \
    __builtin_amdgcn_s_setprio(1); \
    _Pragma("unroll") \
    for (int i_ = 0; i_ < 4; ++i_) { \
        _Pragma("unroll") \
        for (int n_ = 0; n_ < 4; ++n_) \
            acc[(MH) * 4 + i_][n_] = __builtin_amdgcn_mfma_f32_16x16x32_bf16(af_[i_], bf[n_], acc[(MH) * 4 + i_][n_], 0, 0, 0); \
    } \
    __builtin_amdgcn_s_setprio(0); \
    BARRIER(); \
} while (0)

__global__ __launch_bounds__(512, 2) void fused_score_k(
    const unsigned short* __restrict__ Xb, const unsigned short* __restrict__ Wt,
    const float* __restrict__ dec, const float* __restrict__ wconv,
    float* __restrict__ e_out) {
    __shared__ unsigned short As[2][16384];   // [buf][256 rows][64 k] 64KB
    __shared__ unsigned short Bs[2][16384];   // [buf][256 cols][64 k] 64KB
    __shared__ float e_s[256];

    const int tid = threadIdx.x;
    const int lane = tid & 63, wid = tid >> 6;
    const int wr = wid >> 2, wc = wid & 3;          // wave grid 2 (M) x 4 (N)
    const int l15 = lane & 15, lhi = lane >> 4;

    // bijective chunked XCD swizzle: nwg=1504, q=188
    int orig = blockIdx.x;
    int wgid = (orig & 7) * 188 + (orig >> 3);
    const int mtile = wgid >> 3, ct = wgid & 7;
    const int h = ct >> 1, chunk = ct & 1;
    const int r0 = mtile * 256;
    const int bcol0 = h * A_D + chunk * 256;

    if (tid < 256) e_s[tid] = 0.f;

    const int cA0 = (lhi * 8) ^ ((l15 & 7) << 3);
    const int cA1 = (32 + lhi * 8) ^ ((l15 & 7) << 3);
    const int arow = wr * 128 + l15;
    const int bcol = wc * 64 + l15;

    f32x4 acc[8][4];
#pragma unroll
    for (int m = 0; m < 8; ++m)
#pragma unroll
        for (int n2 = 0; n2 < 4; ++n2) {
            f32x4 z = {0.f, 0.f, 0.f, 0.f};
            acc[m][n2] = z;
        }

    stage_A_half(Xb, As[0], 0, 0, r0, tid);
    stage_A_half(Xb, As[0], 1, 0, r0, tid);
    stage_B_half(Wt, Bs[0], 0, 0, bcol0, tid);
    stage_B_half(Wt, Bs[0], 1, 0, bcol0, tid);
    stage_A_half(Xb, As[1], 0, 64, r0, tid);
    asm volatile("s_waitcnt vmcnt(2)" ::: "memory");
    __builtin_amdgcn_s_barrier();
    asm volatile("" ::: "memory");

    s8v bf[4];
    for (int kt = 0; kt < 16; ++kt) {
        const int cur = kt & 1, nxt = cur ^ 1;
        unsigned short* Ac = As[cur];
        unsigned short* Bc = Bs[cur];
        const int kbn = (kt + 1) << 6;
        PHASE(cA0, 0, { if (kt < 15) stage_A_half(Xb, As[nxt], 1, kbn, r0, tid); });
        PHASE(cA0, 1, { if (kt < 15) stage_B_half(Wt, Bs[nxt], 0, kbn, bcol0, tid); });
        PHASE(cA1, 0, { if (kt < 15) stage_B_half(Wt, Bs[nxt], 1, kbn, bcol0, tid); });
        PHASE(cA1, 1, {});
        if (kt < 14) {
            stage_A_half(Xb, As[cur], 0, (kt + 2) << 6, r0, tid);
            asm volatile("s_waitcnt vmcnt(2)" ::: "memory");
        } else if (kt == 14) {
            asm volatile("s_waitcnt vmcnt(0)" ::: "memory");
        }
        BARRIER();
    }

    // fused epilogue: + dec, tanh, * w_conv, sum over a-cols (butterfly over l15), LDS atomic
    float wv[4];
#pragma unroll
    for (int n2 = 0; n2 < 4; ++n2)
        wv[n2] = wconv[bcol0 + wc * 64 + n2 * 16 + l15];
#pragma unroll
    for (int m = 0; m < 8; ++m) {
#pragma unroll
        for (int rg = 0; rg < 4; ++rg) {
            int row_l = wr * 128 + m * 16 + lhi * 4 + rg;
            int grow = r0 + row_l;
            if (grow < MROWS) {
                int nn = (int)((unsigned)grow / 1500u);
                const float* dsl = dec + (size_t)nn * HA_D + bcol0 + wc * 64 + l15;
                float s = 0.f;
#pragma unroll
                for (int n2 = 0; n2 < 4; ++n2) {
                    float v = acc[m][n2][rg] + dsl[n2 * 16];
                    s += wv[n2] * fast_tanh(v);
                }
                s += __shfl_xor(s, 1); s += __shfl_xor(s, 2);
                s += __shfl_xor(s, 4); s += __shfl_xor(s, 8);
                if (l15 == 0) atomicAdd(&e_s[row_l], s);
            }
        }
    }
    __syncthreads();
    if (tid < 256) {
        int grow = r0 + tid;
        if (grow < MROWS) {
            int nn = grow / 1500, tt = grow - nn * 1500;
            atomicAdd(&e_out[(size_t)(nn * H_N + h) * T_S + tt], e_s[tid]);
        }
    }
}

// ============ masked softmax over T -> ali; also zeroes the ctx output region ============
__global__ void softmax_k(const float* __restrict__ e, const int* __restrict__ enc_len,
                          float* __restrict__ ali, float* __restrict__ ctx_zero) {
    const int tid = threadIdx.x, lane = tid & 63, wid = tid >> 6;
    ctx_zero[blockIdx.x * 256 + tid] = 0.f;   // 128 blocks x 256 = 32768 = ctx size
    const int n = blockIdx.x >> 2;
    const int len = enc_len[n];
    const float* row = e + (size_t)blockIdx.x * T_S;
    float* orow = ali + (size_t)blockIdx.x * T_S;
    __shared__ float red[4];
    float p[6];
    float mx = -__builtin_inff();
#pragma unroll
    for (int i = 0; i < 6; ++i) {
        int t = tid + i * 256;
        float v = -__builtin_inff();
        if (t < T_S && t < len) v = row[t];
        p[i] = v;
        mx = fmaxf(mx, v);
    }
#pragma unroll
    for (int o = 32; o; o >>= 1) mx = fmaxf(mx, __shfl_xor(mx, o));
    if (lane == 0) red[wid] = mx;
    __syncthreads();
    mx = fmaxf(fmaxf(red[0], red[1]), fmaxf(red[2], red[3]));
    __syncthreads();
    float sum = 0.f;
#pragma unroll
    for (int i = 0; i < 6; ++i) {
        float qv = (p[i] == -__builtin_inff()) ? 0.f : __expf(p[i] - mx);
        p[i] = qv;
        sum += qv;
    }
#pragma unroll
    for (int o = 32; o; o >>= 1) sum += __shfl_xor(sum, o);
    if (lane == 0) red[wid] = sum;
    __syncthreads();
    sum = red[0] + red[1] + red[2] + red[3];
    float inv = 1.0f / sum;
#pragma unroll
    for (int i = 0; i < 6; ++i) {
        int t = tid + i * 256;
        if (t < T_S) orow[t] = p[i] * inv;
    }
}

// ============ wenc[n,h,d] = sum_t ali[n,h,t] * enc_pad[n,t,d] (vectorized bf16 loads) ============
__global__ void wenc_k(const unsigned short* __restrict__ Xb, const float* __restrict__ ali,
                       float* __restrict__ wenc) {
    const int tid = threadIdx.x;                        // 128
    const int n = blockIdx.x & 31, dc = (blockIdx.x >> 5) & 1, tq = blockIdx.x >> 6;
    const int d0 = dc * 512 + tid * 4;
    const int t0 = tq * 375;
    __shared__ float alis[4][376];
    for (int i = tid; i < 1500; i += 128) {
        int hh = i / 375, tt = i - hh * 375;
        alis[hh][tt] = ali[(size_t)(n * H_N + hh) * T_S + t0 + tt];
    }
    __syncthreads();
    float a[4][4] = {};
    const unsigned short* xp = Xb + (size_t)(n * T_S + t0) * ENC_D + d0;
#pragma unroll 2
    for (int t = 0; t < 375; ++t) {
        ushort4 xv = *(const ushort4*)&xp[(size_t)t * ENC_D];
        float x0 = bf2f(xv.x), x1 = bf2f(xv.y), x2 = bf2f(xv.z), x3 = bf2f(xv.w);
#pragma unroll
        for (int hh = 0; hh < 4; ++hh) {
            float al = alis[hh][t];
            a[hh][0] = fmaf(al, x0, a[hh][0]);
            a[hh][1] = fmaf(al, x1, a[hh][1]);
            a[hh][2] = fmaf(al, x2, a[hh][2]);
            a[hh][3] = fmaf(al, x3, a[hh][3]);
        }
    }
#pragma unroll
    for (int hh = 0; hh < 4; ++hh)
#pragma unroll
        for (int j = 0; j < 4; ++j)
            atomicAdd(&wenc[(size_t)(n * H_N + hh) * ENC_D + d0 + j], a[hh][j]);
}

extern "C" void kernel_launch(void* const* d_in, const int* in_sizes, int n_in,
                              void* d_out, int out_size, void* d_ws, size_t ws_size,
                              hipStream_t stream) {
    const float* enc_pad  = (const float*)d_in[0];
    const int*   enc_len  = (const int*)d_in[1];
    const float* dec_prev = (const float*)d_in[2];
    // d_in[3] = ali_prev (unused by forward)
    const float* W_enc    = (const float*)d_in[4];
    const float* b_enc    = (const float*)d_in[5];
    const float* W_key    = (const float*)d_in[6];
    const float* W_dec    = (const float*)d_in[7];
    const float* W_ctx    = (const float*)d_in[8];
    const float* b_ctx    = (const float*)d_in[9];
    const float* w_conv   = (const float*)d_in[10];

    char* ws = (char*)d_ws;
    unsigned short* Xb = (unsigned short*)ws;                 // 48000*1024*2 = 98,304,000
    unsigned short* Wt = (unsigned short*)(ws + 98304000);    // 2048*1024*2 =  4,194,304
    // zero-range (one memset): dp | e | wenc | cpre, contiguous
    float* dp   = (float*)(ws + 102498304);                   // 32*2048*4   =    262,144
    float* e    = (float*)(ws + 102760448);                   // 192000*4    =    768,000
    float* wenc = (float*)(ws + 103528448);                   // 131072*4    =    524,288
    float* cpre = (float*)(ws + 104052736);                   // 65536*4     =    262,144

    float* ali = (float*)d_out;            // 192000
    float* ctx = ((float*)d_out) + 192000; // 32768

    hipMemsetAsync(ws + 102498304, 0, 1816576, stream);
    prep_k<<<3640, 256, 0, stream>>>(enc_pad, W_key, dec_prev, W_dec, Xb, Wt, dp);
    fused_score_k<<<1504, 512, 0, stream>>>(Xb, Wt, dp, w_conv, e);
    softmax_k<<<128, 256, 0, stream>>>(e, enc_len, ali, ctx);
    wenc_k<<<256, 128, 0, stream>>>(Xb, ali, wenc);
    // ctxpre[n][col] = wenc[n, col>>9, :] @ W_enc[:, col] + b_enc:  8ct x 16ks
    skinny_k<<<128, 256, 0, stream>>>(wenc, W_enc, b_enc, cpre, HA_D, 7, 3, 4096, 1024);
    // ctx[n][j] = cpre[n,:] @ W_ctx[:, j] + b_ctx:  4ct x 32ks
    skinny_k<<<128, 256, 0, stream>>>(cpre, W_ctx, b_ctx, ctx, ENC_D, 3, 2, 2048, 0);
}

// Round 5
// 405.461 us; speedup vs baseline: 1.9221x; 1.4056x over previous
//
#include <hip/hip_runtime.h>
#include <hip/hip_bf16.h>

// MHCtxAttention: N=32, T=1500, ENC=1024, DEC=1024, A=512, H=4, HA=2048
// Outputs: ali (N*H*T = 192000 f32), ctx (N*1024 = 32768 f32), concat in d_out.

#define N_B   32
#define T_S   1500
#define ENC_D 1024
#define HA_D  2048
#define A_D   512
#define H_N   4
#define MROWS 48000   // N_B * T_S

typedef short s8v  __attribute__((ext_vector_type(8)));
typedef float f32x4 __attribute__((ext_vector_type(4)));

__device__ __forceinline__ unsigned short f2bf(float f) {
    unsigned u = __float_as_uint(f);
    unsigned r = (u + 0x7FFFu + ((u >> 16) & 1u)) >> 16;
    return (unsigned short)r;
}
__device__ __forceinline__ float bf2f(unsigned short b) {
    return __uint_as_float(((unsigned)b) << 16);
}
__device__ __forceinline__ float fast_tanh(float x) {
    float e2 = __expf(2.0f * x);
    return 1.0f - __fdividef(2.0f, e2 + 1.0f);
}
__device__ __forceinline__ void gload_lds16(const void* g, void* l) {
    __builtin_amdgcn_global_load_lds(
        (const unsigned int __attribute__((address_space(1)))*)g,
        (unsigned int __attribute__((address_space(3)))*)l, 16, 0, 0);
}

// ============ skinny GEMM body: Y[n][c] (+)= sum_k X[n][k] * W[k][c]  (M=32) ============
// block: 256 cols (c0=ct*256) x 32 n x 64-k chunk (k0=ks*64). W read coalesced float4,
// X chunk staged transposed [kk][n] in LDS, consumed as wave-uniform broadcast b128.
// Accumulate via f32 atomicAdd; bias folded into ks==0 blocks. Y must be pre-zeroed.
__device__ __forceinline__ void skinny_body(
    int bid, const float* __restrict__ X, const float* __restrict__ W,
    const float* __restrict__ bias, float* __restrict__ Y,
    int Ncols, int ct_mask, int ct_shift, int xA, int xB, float* xT /* >= 64*36 floats */) {
    const int tid = threadIdx.x;
    const int ct = bid & ct_mask, ks = bid >> ct_shift;
    const int c0 = ct << 8, k0 = ks << 6;
    const int hsel = c0 >> 9;
    {
        const int n = tid >> 3, kk0 = (tid & 7) << 3;
        const float* xr = X + (size_t)n * xA + hsel * xB + k0 + kk0;
        float4 v0 = *(const float4*)xr;
        float4 v1 = *(const float4*)(xr + 4);
        xT[(kk0 + 0) * 36 + n] = v0.x;
        xT[(kk0 + 1) * 36 + n] = v0.y;
        xT[(kk0 + 2) * 36 + n] = v0.z;
        xT[(kk0 + 3) * 36 + n] = v0.w;
        xT[(kk0 + 4) * 36 + n] = v1.x;
        xT[(kk0 + 5) * 36 + n] = v1.y;
        xT[(kk0 + 6) * 36 + n] = v1.z;
        xT[(kk0 + 7) * 36 + n] = v1.w;
    }
    __syncthreads();
    const int w = tid >> 6, lane = tid & 63;
    f32x4 acc[8];
    if (bias != nullptr && ks == 0) {
        f32x4 bv = *(const f32x4*)&bias[c0 + (lane << 2)];
#pragma unroll
        for (int j = 0; j < 8; ++j) acc[j] = bv;
    } else {
#pragma unroll
        for (int j = 0; j < 8; ++j) { f32x4 z = {0.f, 0.f, 0.f, 0.f}; acc[j] = z; }
    }
    const float* Wp = W + (size_t)k0 * Ncols + c0 + (lane << 2);
#pragma unroll 4
    for (int kk = 0; kk < 64; ++kk) {
        f32x4 wf = *(const f32x4*)(Wp + (size_t)kk * Ncols);
        f32x4 xlo = *(const f32x4*)&xT[kk * 36 + w * 8];
        f32x4 xhi = *(const f32x4*)&xT[kk * 36 + w * 8 + 4];
#pragma unroll
        for (int j = 0; j < 4; ++j) {
            acc[j]     += xlo[j] * wf;
            acc[4 + j] += xhi[j] * wf;
        }
    }
#pragma unroll
    for (int j = 0; j < 8; ++j) {
        float* yp = Y + (size_t)(w * 8 + j) * Ncols + c0 + (lane << 2);
#pragma unroll
        for (int i = 0; i < 4; ++i) atomicAdd(yp + i, acc[j][i]);
    }
}

__global__ __launch_bounds__(256) void skinny_k(
    const float* __restrict__ X, const float* __restrict__ W,
    const float* __restrict__ bias, float* __restrict__ Y,
    int Ncols, int ct_mask, int ct_shift, int xA, int xB) {
    __shared__ float xT[64 * 36];
    skinny_body(blockIdx.x, X, W, bias, Y, Ncols, ct_mask, ct_shift, xA, xB, xT);
}

// ============ prep kernel: [0,128) dec_part skinny | [128,640) W_key transpose | [640,3640) cast ====
__global__ __launch_bounds__(256) void prep_k(
    const float* __restrict__ enc_pad, const float* __restrict__ Wk,
    const float* __restrict__ dec_prev, const float* __restrict__ W_dec,
    unsigned short* __restrict__ Xb, unsigned short* __restrict__ Wt,
    float* __restrict__ dp) {
    __shared__ float shmem[64 * 65];
    const int b = blockIdx.x;
    const int tid = threadIdx.x;
    if (b < 128) {
        skinny_body(b, dec_prev, W_dec, nullptr, dp, HA_D, 7, 3, 1024, 0, shmem);
    } else if (b < 640) {
        float (*ld)[65] = (float(*)[65])shmem;
        const int bb = b - 128;
        const int tx = tid & 63, ty = tid >> 6;
        const int c0 = (bb & 31) * 64, d0 = (bb >> 5) * 64;
#pragma unroll
        for (int j = 0; j < 16; ++j)
            ld[ty + 4 * j][tx] = Wk[(size_t)(d0 + ty + 4 * j) * HA_D + c0 + tx];
        __syncthreads();
#pragma unroll
        for (int j = 0; j < 16; ++j)
            Wt[(size_t)(c0 + ty + 4 * j) * ENC_D + d0 + tx] = f2bf(ld[tx][ty + 4 * j]);
    } else {
        const float4* in = (const float4*)enc_pad;
        ushort4* out = (ushort4*)Xb;
        for (int i = (b - 640) * 256 + tid; i < 12288000; i += 3000 * 256) {
            float4 v = in[i];
            ushort4 o;
            o.x = f2bf(v.x); o.y = f2bf(v.y); o.z = f2bf(v.z); o.w = f2bf(v.w);
            out[i] = o;
        }
    }
}

// ============ fused score GEMM, m97-exact: 128x256 tile, single-buffer, 3 blocks/CU ============
// grid 3000 = 375 mtiles x 8 col-tiles.  e_out must be pre-zeroed (2 col-tiles add per head elem).
__global__ __launch_bounds__(512) void fused_score_k(
    const unsigned short* __restrict__ Xb, const unsigned short* __restrict__ Wt,
    const float* __restrict__ dec, const float* __restrict__ wconv,
    const int* __restrict__ enc_len, float* __restrict__ e_out) {
    __shared__ unsigned short As[128 * 64];   // 16 KB
    __shared__ unsigned short Bs[256 * 64];   // 32 KB
    __shared__ float e_s[128];

    const int tid = threadIdx.x;
    const int lane = tid & 63, wid = tid >> 6;
    const int wr = wid >> 2, wc = wid & 3;          // wave grid 2 (M) x 4 (N)
    const int l15 = lane & 15, lhi = lane >> 4;

    // bijective XCD swizzle: 3000 = 8 * 375; 8 consecutive wgids share one mtile (A reuse on-XCD)
    int orig = blockIdx.x;
    int wgid = (orig & 7) * 375 + (orig >> 3);
    const int mtile = wgid >> 3, nt = wgid & 7;
    const int r0 = mtile * 128;
    const int bcol0 = nt * 256;                     // global HA column base
    const int h = nt >> 1;

    // early-out: whole 128-row stripe masked (softmax ignores e there; e pre-zeroed)
    {
        int n0 = (int)((unsigned)r0 / 1500u);
        int t0 = r0 - n0 * 1500;
        if (t0 + 127 < 1500 && t0 >= enc_len[n0]) return;
    }

    if (tid < 128) e_s[tid] = 0.f;

    // hoisted stage pointers (source pre-swizzled, LDS dest linear)
    const unsigned short* aSrc[2]; int aDst[2];
#pragma unroll
    for (int ld = 0; ld < 2; ++ld) {
        int li = ld * 512 + tid, rowL = li >> 3, c16 = li & 7;
        aSrc[ld] = Xb + (size_t)(r0 + rowL) * ENC_D + ((c16 ^ (rowL & 7)) << 3);
        aDst[ld] = li * 8;
    }
    const unsigned short* bSrc[4]; int bDst[4];
#pragma unroll
    for (int ld = 0; ld < 4; ++ld) {
        int li = ld * 512 + tid, colL = li >> 3, c16 = li & 7;
        bSrc[ld] = Wt + (size_t)(bcol0 + colL) * ENC_D + ((c16 ^ (colL & 7)) << 3);
        bDst[ld] = li * 8;
    }

    const int cA0 = (lhi * 8) ^ ((l15 & 7) << 3);
    const int cA1 = (32 + lhi * 8) ^ ((l15 & 7) << 3);
    const int arow = wr * 64 + l15;
    const int bcol = wc * 64 + l15;

    f32x4 acc[4][4];
#pragma unroll
    for (int m = 0; m < 4; ++m)
#pragma unroll
        for (int n2 = 0; n2 < 4; ++n2) {
            f32x4 z = {0.f, 0.f, 0.f, 0.f};
            acc[m][n2] = z;
        }

    for (int ks = 0; ks < 16; ++ks) {
        const int kb = ks << 6;
#pragma unroll
        for (int ld = 0; ld < 2; ++ld) gload_lds16(aSrc[ld] + kb, As + aDst[ld]);
#pragma unroll
        for (int ld = 0; ld < 4; ++ld) gload_lds16(bSrc[ld] + kb, Bs + bDst[ld]);
        __syncthreads();
#pragma unroll
        for (int kk = 0; kk < 2; ++kk) {
            const int cc = kk ? cA1 : cA0;
            s8v af[4], bv[4];
#pragma unroll
            for (int m = 0; m < 4; ++m)
                af[m] = *(const s8v*)&As[(arow + m * 16) * 64 + cc];
#pragma unroll
            for (int n2 = 0; n2 < 4; ++n2)
                bv[n2] = *(const s8v*)&Bs[(bcol + n2 * 16) * 64 + cc];
#pragma unroll
            for (int m = 0; m < 4; ++m)
#pragma unroll
                for (int n2 = 0; n2 < 4; ++n2)
                    acc[m][n2] = __builtin_amdgcn_mfma_f32_16x16x32_bf16(af[m], bv[n2], acc[m][n2], 0, 0, 0);
        }
        __syncthreads();
    }

    // fused epilogue: + dec, tanh, * w_conv, sum over a-cols (butterfly over l15), LDS atomic
    float wv[4];
#pragma unroll
    for (int n2 = 0; n2 < 4; ++n2)
        wv[n2] = wconv[bcol0 + wc * 64 + n2 * 16 + l15];
#pragma unroll
    for (int m = 0; m < 4; ++m) {
#pragma unroll
        for (int rg = 0; rg < 4; ++rg) {
            int row_l = wr * 64 + m * 16 + lhi * 4 + rg;
            int grow = r0 + row_l;
            int nn = (int)((unsigned)grow / 1500u);
            const float* dsl = dec + (size_t)nn * HA_D + bcol0 + wc * 64 + l15;
            float s = 0.f;
#pragma unroll
            for (int n2 = 0; n2 < 4; ++n2) {
                float v = acc[m][n2][rg] + dsl[n2 * 16];
                s += wv[n2] * fast_tanh(v);
            }
            s += __shfl_xor(s, 1); s += __shfl_xor(s, 2);
            s += __shfl_xor(s, 4); s += __shfl_xor(s, 8);
            if (l15 == 0) atomicAdd(&e_s[row_l], s);
        }
    }
    __syncthreads();
    if (tid < 128) {
        int grow = r0 + tid;
        int nn = grow / 1500, tt = grow - nn * 1500;
        atomicAdd(&e_out[(size_t)(nn * H_N + h) * T_S + tt], e_s[tid]);
    }
}

// ============ masked softmax over T -> ali; also zeroes the ctx output region ============
__global__ void softmax_k(const float* __restrict__ e, const int* __restrict__ enc_len,
                          float* __restrict__ ali, float* __restrict__ ctx_zero) {
    const int tid = threadIdx.x, lane = tid & 63, wid = tid >> 6;
    ctx_zero[blockIdx.x * 256 + tid] = 0.f;   // 128 blocks x 256 = 32768 = ctx size
    const int n = blockIdx.x >> 2;
    const int len = enc_len[n];
    const float* row = e + (size_t)blockIdx.x * T_S;
    float* orow = ali + (size_t)blockIdx.x * T_S;
    __shared__ float red[4];
    float p[6];
    float mx = -__builtin_inff();
#pragma unroll
    for (int i = 0; i < 6; ++i) {
        int t = tid + i * 256;
        float v = -__builtin_inff();
        if (t < T_S && t < len) v = row[t];
        p[i] = v;
        mx = fmaxf(mx, v);
    }
#pragma unroll
    for (int o = 32; o; o >>= 1) mx = fmaxf(mx, __shfl_xor(mx, o));
    if (lane == 0) red[wid] = mx;
    __syncthreads();
    mx = fmaxf(fmaxf(red[0], red[1]), fmaxf(red[2], red[3]));
    __syncthreads();
    float sum = 0.f;
#pragma unroll
    for (int i = 0; i < 6; ++i) {
        float qv = (p[i] == -__builtin_inff()) ? 0.f : __expf(p[i] - mx);
        p[i] = qv;
        sum += qv;
    }
#pragma unroll
    for (int o = 32; o; o >>= 1) sum += __shfl_xor(sum, o);
    if (lane == 0) red[wid] = sum;
    __syncthreads();
    sum = red[0] + red[1] + red[2] + red[3];
    float inv = 1.0f / sum;
#pragma unroll
    for (int i = 0; i < 6; ++i) {
        int t = tid + i * 256;
        if (t < T_S) orow[t] = p[i] * inv;
    }
}

// ============ wenc[n,h,d] = sum_t ali[n,h,t] * enc_pad[n,t,d] ============
// grid 512 = 32 n x 16 t-chunks of 94; 256 threads, ushort4 per thread (d = tid*4)
__global__ __launch_bounds__(256) void wenc_k(const unsigned short* __restrict__ Xb,
                                              const float* __restrict__ ali,
                                              const int* __restrict__ enc_len,
                                              float* __restrict__ wenc) {
    const int tid = threadIdx.x;
    const int n = blockIdx.x & 31, tq = blockIdx.x >> 5;
    const int t0 = tq * 94;
    const int tcnt = (t0 + 94 <= T_S) ? 94 : (T_S - t0);
    if (t0 >= enc_len[n]) return;                    // ali rows all zero; wenc pre-zeroed
    __shared__ float alis[4][94];
    for (int i = tid; i < 376; i += 256) {
        int hh = i / 94, tt = i - hh * 94;
        if (tt < tcnt) alis[hh][tt] = ali[(size_t)(n * H_N + hh) * T_S + t0 + tt];
    }
    __syncthreads();
    const int d0 = tid * 4;
    float a[4][4] = {};
    const unsigned short* xp = Xb + (size_t)(n * T_S + t0) * ENC_D + d0;
#pragma unroll 4
    for (int t = 0; t < tcnt; ++t) {
        ushort4 xv = *(const ushort4*)&xp[(size_t)t * ENC_D];
        float x0 = bf2f(xv.x), x1 = bf2f(xv.y), x2 = bf2f(xv.z), x3 = bf2f(xv.w);
#pragma unroll
        for (int hh = 0; hh < 4; ++hh) {
            float al = alis[hh][t];
            a[hh][0] = fmaf(al, x0, a[hh][0]);
            a[hh][1] = fmaf(al, x1, a[hh][1]);
            a[hh][2] = fmaf(al, x2, a[hh][2]);
            a[hh][3] = fmaf(al, x3, a[hh][3]);
        }
    }
#pragma unroll
    for (int hh = 0; hh < 4; ++hh)
#pragma unroll
        for (int j = 0; j < 4; ++j)
            atomicAdd(&wenc[(size_t)(n * H_N + hh) * ENC_D + d0 + j], a[hh][j]);
}

extern "C" void kernel_launch(void* const* d_in, const int* in_sizes, int n_in,
                              void* d_out, int out_size, void* d_ws, size_t ws_size,
                              hipStream_t stream) {
    const float* enc_pad  = (const float*)d_in[0];
    const int*   enc_len  = (const int*)d_in[1];
    const float* dec_prev = (const float*)d_in[2];
    // d_in[3] = ali_prev (unused by forward)
    const float* W_enc    = (const float*)d_in[4];
    const float* b_enc    = (const float*)d_in[5];
    const float* W_key    = (const float*)d_in[6];
    const float* W_dec    = (const float*)d_in[7];
    const float* W_ctx    = (const float*)d_in[8];
    const float* b_ctx    = (const float*)d_in[9];
    const float* w_conv   = (const float*)d_in[10];

    char* ws = (char*)d_ws;
    unsigned short* Xb = (unsigned short*)ws;                 // 48000*1024*2 = 98,304,000
    unsigned short* Wt = (unsigned short*)(ws + 98304000);    // 2048*1024*2 =  4,194,304
    // zero-range (one memset): dp | e | wenc | cpre, contiguous
    float* dp   = (float*)(ws + 102498304);                   // 32*2048*4   =    262,144
    float* e    = (float*)(ws + 102760448);                   // 192000*4    =    768,000
    float* wenc = (float*)(ws + 103528448);                   // 131072*4    =    524,288
    float* cpre = (float*)(ws + 104052736);                   // 65536*4     =    262,144

    float* ali = (float*)d_out;            // 192000
    float* ctx = ((float*)d_out) + 192000; // 32768

    hipMemsetAsync(ws + 102498304, 0, 1816576, stream);
    prep_k<<<3640, 256, 0, stream>>>(enc_pad, W_key, dec_prev, W_dec, Xb, Wt, dp);
    fused_score_k<<<3000, 512, 0, stream>>>(Xb, Wt, dp, w_conv, enc_len, e);
    softmax_k<<<128, 256, 0, stream>>>(e, enc_len, ali, ctx);
    wenc_k<<<512, 256, 0, stream>>>(Xb, ali, enc_len, wenc);
    // ctxpre[n][col] = wenc[n, col>>9, :] @ W_enc[:, col] + b_enc:  8ct x 16ks
    skinny_k<<<128, 256, 0, stream>>>(wenc, W_enc, b_enc, cpre, HA_D, 7, 3, 4096, 1024);
    // ctx[n][j] = cpre[n,:] @ W_ctx[:, j] + b_ctx:  4ct x 32ks
    skinny_k<<<128, 256, 0, stream>>>(cpre, W_ctx, b_ctx, ctx, ENC_D, 3, 2, 2048, 0);
}